// Round 2
// baseline (92.552 us; speedup 1.0000x reference)
//
#include <hip/hip_runtime.h>
#include <hip/hip_bf16.h>

// Closed form for the quantum part:
//   q_out[b] = prod_{i=1..6} cos(x_q[b,i] + q_params[i])
// Derivation: CNOT ring (0,1)..(6,0) permutes basis labels; tracking the
// sequential XORs, final bit0 = y1^y2^...^y6 of the initial product state, so
// <Z0> = prod_{i=1..6} E[(-1)^{y_i}] = prod cos^2(h_i)-sin^2(h_i)
//      = prod cos(x_i + w_i).  Qubit 0 drops out entirely.
// Then MLP: [q, x_c] (17) -> relu(32) -> relu(16) -> 1.
//
// ALL tensors are float32 (per the reference; round-1 NaN came from
// misreading fp32 buffers as bf16). Weights are read with uniform indices
// so the compiler emits s_load (scalar cache) and FMAs take SGPR operands.

#define NQ 7
#define NC 16

__global__ __launch_bounds__(256) void hybrid_kernel(
    const float* __restrict__ xq,
    const float* __restrict__ xc,
    const float* __restrict__ qp,
    const float* __restrict__ W1,
    const float* __restrict__ b1,
    const float* __restrict__ W2,
    const float* __restrict__ b2,
    const float* __restrict__ W3,
    const float* __restrict__ b3,
    float* __restrict__ out,
    int nrows) {
    int b = blockIdx.x * 256 + threadIdx.x;
    if (b >= nrows) return;

    // ---- quantum feature: product of 6 cosines (qubit 0 drops out) ----
    const float* xqr = xq + (size_t)b * NQ;
    float q = 1.0f;
#pragma unroll
    for (int i = 1; i < NQ; ++i) {
        q *= __cosf(xqr[i] + qp[i]);
    }

    // ---- build combined[17] = [q, x_c] ----
    float comb[17];
    comb[0] = q;
    // x_c row: 16 floats = 64 B, rows 64B-aligned -> four dwordx4 loads
    const float4* xcv = (const float4*)(xc + (size_t)b * NC);
#pragma unroll
    for (int i = 0; i < 4; ++i) {
        float4 v = xcv[i];
        comb[1 + 4 * i + 0] = v.x;
        comb[1 + 4 * i + 1] = v.y;
        comb[1 + 4 * i + 2] = v.z;
        comb[1 + 4 * i + 3] = v.w;
    }

    // ---- layer 1: 17 -> 32, relu ----
    float h1[32];
#pragma unroll
    for (int j = 0; j < 32; ++j) h1[j] = b1[j];
#pragma unroll
    for (int k = 0; k < 17; ++k) {
        float a = comb[k];
#pragma unroll
        for (int j = 0; j < 32; ++j) h1[j] = fmaf(a, W1[k * 32 + j], h1[j]);
    }
#pragma unroll
    for (int j = 0; j < 32; ++j) h1[j] = fmaxf(h1[j], 0.0f);

    // ---- layer 2: 32 -> 16, relu ----
    float h2[16];
#pragma unroll
    for (int j = 0; j < 16; ++j) h2[j] = b2[j];
#pragma unroll
    for (int k = 0; k < 32; ++k) {
        float a = h1[k];
#pragma unroll
        for (int j = 0; j < 16; ++j) h2[j] = fmaf(a, W2[k * 16 + j], h2[j]);
    }
#pragma unroll
    for (int j = 0; j < 16; ++j) h2[j] = fmaxf(h2[j], 0.0f);

    // ---- layer 3: 16 -> 1 ----
    float o = b3[0];
#pragma unroll
    for (int j = 0; j < 16; ++j) o = fmaf(h2[j], W3[j], o);

    out[b] = o;
}

extern "C" void kernel_launch(void* const* d_in, const int* in_sizes, int n_in,
                              void* d_out, int out_size, void* d_ws, size_t ws_size,
                              hipStream_t stream) {
    const float* xq = (const float*)d_in[0];
    const float* xc = (const float*)d_in[1];
    const float* qp = (const float*)d_in[2];
    const float* W1 = (const float*)d_in[3];
    const float* b1 = (const float*)d_in[4];
    const float* W2 = (const float*)d_in[5];
    const float* b2 = (const float*)d_in[6];
    const float* W3 = (const float*)d_in[7];
    const float* b3 = (const float*)d_in[8];
    float* out = (float*)d_out;

    int nrows = in_sizes[0] / NQ;  // B = 262144

    int grid = (nrows + 255) / 256;
    hybrid_kernel<<<grid, 256, 0, stream>>>(xq, xc, qp, W1, b1, W2, b2, W3, b3,
                                            out, nrows);
}